// Round 7
// baseline (28.126 us; speedup 1.0000x reference)
//
#include <hip/hip_runtime.h>
#include <hip/hip_fp16.h>
#include <math.h>

typedef _Float16 half8 __attribute__((ext_vector_type(8)));
typedef _Float16 half4 __attribute__((ext_vector_type(4)));
typedef __fp16 fp16x2 __attribute__((ext_vector_type(2)));
typedef float f32x4 __attribute__((ext_vector_type(4)));

#define S_LEN 2048
#define NH 8
#define DH 64
#define HD (NH*DH)
#define BQ 64
#define SPAN (BQ + 256)      // 320 keys per block (W<=128)
#define NT 256               // 4 waves; 40 KB LDS -> 3 blocks/CU, 12 waves/CU

// Sliding-window attention, f16 MFMA flash kernel, V-only LDS.
// Swapped QK^T: S^T = K*Q^T -> lane (c,g) holds 8 scores for query q0+16*wid+c.
// K is NOT staged: fragments are read per-tile from global fp32 (L2-resident
// panel, 512 KB per (b,h) under the XCD swizzle), double-buffered in registers
// one tile ahead, converted with v_cvt_pkrtz at use. Only V^T (40 KB f16,
// 16B-chunk swizzle) is staged -> one barrier, 3 blocks/CU, and K traffic
// streams through the whole tile loop instead of bursting up front.
// PV: O^T = V^T * P^T with K-axis permutation sigma(8g+e)=4g+(e&3)+16*(e>>2)
// so the P fragment is the lane's own 8 probabilities (no repack).
__global__ __launch_bounds__(NT, 3)
void swa_mfma(const float* __restrict__ qg, const float* __restrict__ kg,
              const float* __restrict__ vg, const int* __restrict__ wptr,
              float* __restrict__ outg)
{
    __shared__ __align__(16) unsigned short Vt[DH * SPAN];  // [dim][key] f16, swizzled

    int W = *wptr; if (W > 128) W = 128;

    const int t = threadIdx.x;
    // XCD-aware bijective swizzle (gridDim.x = 512): each XCD's 64 contiguous
    // work-ids = all 32 q-tiles of 2 (b,h) panels -> K/V panels L2-resident.
    int bid = blockIdx.x;
    bid = (bid & 7) * (gridDim.x >> 3) + (bid >> 3);
    const int qt = bid & 31, h = (bid >> 5) & 7, b = bid >> 8;
    const int i0 = qt * BQ, s0 = i0 - W;

    const float* kbh = kg + (size_t)b * S_LEN * HD + h * DH;
    const float* vbh = vg + (size_t)b * S_LEN * HD + h * DH;

    const int wid = t >> 6, lane = t & 63, c = lane & 15, g = lane >> 4;
    const int q = i0 + wid * 16 + c;

    // ---- Q loads issued first (overlap with staging) ----
    const float* qrow = qg + (size_t)b * S_LEN * HD + h * DH + (size_t)q * HD;
    const f32x4 qf0 = *(const f32x4*)(qrow + g * 8);
    const f32x4 qf1 = *(const f32x4*)(qrow + g * 8 + 4);
    const f32x4 qf2 = *(const f32x4*)(qrow + 32 + g * 8);
    const f32x4 qf3 = *(const f32x4*)(qrow + 32 + g * 8 + 4);

    // ---- stage V^T: 80 kq * 16 dq = 1280 tasks, 5 clean iterations ----
    #pragma unroll
    for (int it = 0; it < 5; ++it) {
        const int task = t + it * NT;
        const int kq = task >> 4, dq = task & 15;
        f32x4 r[4];
        #pragma unroll
        for (int jj = 0; jj < 4; ++jj) {
            const int j = s0 + kq * 4 + jj;
            f32x4 f = {0,0,0,0};
            if ((unsigned)j < S_LEN) f = *(const f32x4*)(vbh + (size_t)j * HD + dq * 4);
            r[jj] = f;
        }
        #pragma unroll
        for (int i = 0; i < 4; ++i) {
            const int dim = dq * 4 + i;
            half4 w = { (_Float16)r[0][i], (_Float16)r[1][i],
                        (_Float16)r[2][i], (_Float16)r[3][i] };
            *(half4*)(&Vt[dim * SPAN + (((kq >> 1) ^ (dim & 7)) << 3) + ((kq & 1) << 2)]) = w;
        }
    }

    // ---- Q fragments (1/sqrt(D)*log2(e) folded; exp -> exp2 domain) ----
    half8 qa0, qa1;
    {
        const float qs = 0.18033688011112042f;  // 0.125 * log2(e)
        #pragma unroll
        for (int e = 0; e < 4; ++e) {
            qa0[e] = (_Float16)(qf0[e] * qs); qa0[4+e] = (_Float16)(qf1[e] * qs);
            qa1[e] = (_Float16)(qf2[e] * qs); qa1[4+e] = (_Float16)(qf3[e] * qs);
        }
    }

    const int c7 = c & 7;
    int lo = q - W; if (lo < 0) lo = 0;
    int hi = q + W; if (hi > S_LEN - 1) hi = S_LEN - 1;
    const unsigned rng = (unsigned)(hi - lo);
    const int qw0 = i0 + wid * 16;          // first query row of this wave

    int ts = wid >> 1;
    const int ts0 = (s0 < 0) ? ((-s0) >> 5) : 0;
    if (ts0 > ts) ts = ts0;
    const int te_w = (16 * wid + 15 + 2 * W) >> 5;
    const int te_s = (S_LEN - 1 - s0) >> 5;
    const int te = te_w < te_s ? te_w : te_s;

    float m = -1e4f, l = 0.f;
    f32x4 o0 = {0,0,0,0}, o1 = {0,0,0,0}, o2 = {0,0,0,0}, o3 = {0,0,0,0};

    // K fragment raw loads: rows (j0+c) and (j0+16+c), dims [8g,8g+8) and [8g+32,8g+40)
    auto loadKraw = [&](int t32, f32x4 (&kr)[4][2]) {
        const int j0 = s0 + t32 * 32;
        int rA = j0 + c;      rA = rA < 0 ? 0 : (rA > S_LEN - 1 ? S_LEN - 1 : rA);
        int rB = j0 + 16 + c; rB = rB < 0 ? 0 : (rB > S_LEN - 1 ? S_LEN - 1 : rB);
        const float* pA = kbh + (size_t)rA * HD + g * 8;
        const float* pB = kbh + (size_t)rB * HD + g * 8;
        kr[0][0] = *(const f32x4*)(pA);      kr[0][1] = *(const f32x4*)(pA + 4);
        kr[1][0] = *(const f32x4*)(pA + 32); kr[1][1] = *(const f32x4*)(pA + 36);
        kr[2][0] = *(const f32x4*)(pB);      kr[2][1] = *(const f32x4*)(pB + 4);
        kr[3][0] = *(const f32x4*)(pB + 32); kr[3][1] = *(const f32x4*)(pB + 36);
    };
    auto mkfrag = [](const f32x4& a, const f32x4& b) -> half8 {
        fp16x2 p0 = __builtin_amdgcn_cvt_pkrtz(a[0], a[1]);
        fp16x2 p1 = __builtin_amdgcn_cvt_pkrtz(a[2], a[3]);
        fp16x2 p2 = __builtin_amdgcn_cvt_pkrtz(b[0], b[1]);
        fp16x2 p3 = __builtin_amdgcn_cvt_pkrtz(b[2], b[3]);
        half8 r;
        r[0]=(_Float16)p0[0]; r[1]=(_Float16)p0[1]; r[2]=(_Float16)p1[0]; r[3]=(_Float16)p1[1];
        r[4]=(_Float16)p2[0]; r[5]=(_Float16)p2[1]; r[6]=(_Float16)p3[0]; r[7]=(_Float16)p3[1];
        return r;
    };

    auto computeTile = [&](int t32, f32x4 (&kr)[4][2]) {
        // ---- QK^T (swapped): S^T = K * Q^T ----
        half8 k00 = mkfrag(kr[0][0], kr[0][1]);
        half8 k01 = mkfrag(kr[1][0], kr[1][1]);
        half8 k10 = mkfrag(kr[2][0], kr[2][1]);
        half8 k11 = mkfrag(kr[3][0], kr[3][1]);
        f32x4 st0 = {0,0,0,0}, st1 = {0,0,0,0};
        __builtin_amdgcn_s_setprio(1);
        st0 = __builtin_amdgcn_mfma_f32_16x16x32_f16(k00, qa0, st0, 0, 0, 0);
        st0 = __builtin_amdgcn_mfma_f32_16x16x32_f16(k01, qa1, st0, 0, 0, 0);
        st1 = __builtin_amdgcn_mfma_f32_16x16x32_f16(k10, qa0, st1, 0, 0, 0);
        st1 = __builtin_amdgcn_mfma_f32_16x16x32_f16(k11, qa1, st1, 0, 0, 0);
        __builtin_amdgcn_s_setprio(0);

        // ---- mask (skipped on interior tiles) + online softmax ----
        const int j0 = s0 + t32 * 32;
        float sv0[4], sv1[4];
        const bool allv = (j0 >= 0) && (j0 + 31 < S_LEN) &&
                          (j0 >= qw0 + 15 - W) && (j0 + 31 <= qw0 + W);
        if (allv) {
            #pragma unroll
            for (int r = 0; r < 4; ++r) { sv0[r] = st0[r]; sv1[r] = st1[r]; }
        } else {
            const int kb = j0 + 4 * g;
            #pragma unroll
            for (int r = 0; r < 4; ++r) {
                sv0[r] = ((unsigned)(kb + r - lo) <= rng)      ? st0[r] : -30000.f;
                sv1[r] = ((unsigned)(kb + 16 + r - lo) <= rng) ? st1[r] : -30000.f;
            }
        }
        float tmax = fmaxf(fmaxf(fmaxf(sv0[0], sv0[1]), fmaxf(sv0[2], sv0[3])),
                           fmaxf(fmaxf(sv1[0], sv1[1]), fmaxf(sv1[2], sv1[3])));
        tmax = fmaxf(tmax, __shfl_xor(tmax, 16));
        tmax = fmaxf(tmax, __shfl_xor(tmax, 32));
        if (__any(tmax > m)) {   // deferred rescale
            const float newm = fmaxf(m, tmax);
            const float alpha = exp2f(m - newm);
            m = newm;
            l *= alpha;
            o0 *= alpha; o1 *= alpha; o2 *= alpha; o3 *= alpha;
        }
        float p0[4], p1[4], ls = 0.f;
        #pragma unroll
        for (int r = 0; r < 4; ++r) {
            p0[r] = exp2f(sv0[r] - m);
            p1[r] = exp2f(sv1[r] - m);
            ls += p0[r] + p1[r];
        }
        l += ls;
        half8 pb;
        #pragma unroll
        for (int r = 0; r < 4; ++r) { pb[r] = (_Float16)p0[r]; pb[4+r] = (_Float16)p1[r]; }

        // ---- PV: O^T += V^T * P^T ----
        const int cb = 4 * t32 + (g >> 1);
        const int off1 = ((cb ^ c7) << 3) + ((g & 1) << 2);
        const int off2 = (((cb + 2) ^ c7) << 3) + ((g & 1) << 2);
        __builtin_amdgcn_s_setprio(1);
#define PV_STEP(DF, OACC) { \
        const unsigned short* vrow = &Vt[(16 * DF + c) * SPAN]; \
        half4 vlo = *(const half4*)(vrow + off1); \
        half4 vhi = *(const half4*)(vrow + off2); \
        half8 vf; \
        vf[0]=vlo[0]; vf[1]=vlo[1]; vf[2]=vlo[2]; vf[3]=vlo[3]; \
        vf[4]=vhi[0]; vf[5]=vhi[1]; vf[6]=vhi[2]; vf[7]=vhi[3]; \
        OACC = __builtin_amdgcn_mfma_f32_16x16x32_f16(vf, pb, OACC, 0, 0, 0); }
        PV_STEP(0, o0)
        PV_STEP(1, o1)
        PV_STEP(2, o2)
        PV_STEP(3, o3)
#undef PV_STEP
        __builtin_amdgcn_s_setprio(0);
    };

    // ---- issue first K-tile loads before the staging barrier ----
    f32x4 krA[4][2], krB[4][2];
    loadKraw(ts, krA);

    __syncthreads();   // V^T tile ready (single barrier in the kernel)

    // ---- tile loop, 1-deep register double-buffer on K ----
    int t32 = ts;
    while (t32 <= te) {
        if (t32 < te) loadKraw(t32 + 1, krB);
        computeTile(t32, krA);
        ++t32;
        if (t32 > te) break;
        if (t32 < te) loadKraw(t32 + 1, krA);
        computeTile(t32, krB);
        ++t32;
    }

    // ---- epilogue ----
    l += __shfl_xor(l, 16);
    l += __shfl_xor(l, 32);
    const float inv = 1.0f / l;
    float* orow = outg + (size_t)b * S_LEN * HD + h * DH + (size_t)q * HD + 4 * g;
    { float4 w; w.x=o0[0]*inv; w.y=o0[1]*inv; w.z=o0[2]*inv; w.w=o0[3]*inv; *(float4*)(orow)      = w; }
    { float4 w; w.x=o1[0]*inv; w.y=o1[1]*inv; w.z=o1[2]*inv; w.w=o1[3]*inv; *(float4*)(orow + 16) = w; }
    { float4 w; w.x=o2[0]*inv; w.y=o2[1]*inv; w.z=o2[2]*inv; w.w=o2[3]*inv; *(float4*)(orow + 32) = w; }
    { float4 w; w.x=o3[0]*inv; w.y=o3[1]*inv; w.z=o3[2]*inv; w.w=o3[3]*inv; *(float4*)(orow + 48) = w; }
}

extern "C" void kernel_launch(void* const* d_in, const int* in_sizes, int n_in,
                              void* d_out, int out_size, void* d_ws, size_t ws_size,
                              hipStream_t stream) {
    const float* q = (const float*)d_in[0];
    const float* k = (const float*)d_in[1];
    const float* v = (const float*)d_in[2];
    const int*   w = (const int*)d_in[3];
    float* out = (float*)d_out;

    const int nblocks = 2 * NH * (S_LEN / BQ);   // 512
    swa_mfma<<<dim3(nblocks), dim3(NT), 0, stream>>>(q, k, v, w, out);
}

// Round 8
// 24.578 us; speedup vs baseline: 1.1444x; 1.1444x over previous
//
#include <hip/hip_runtime.h>
#include <hip/hip_fp16.h>
#include <math.h>

typedef _Float16 half8 __attribute__((ext_vector_type(8)));
typedef _Float16 half4 __attribute__((ext_vector_type(4)));
typedef float f32x4 __attribute__((ext_vector_type(4)));
typedef unsigned short u16x8 __attribute__((ext_vector_type(8)));

#define S_LEN 2048
#define NH 8
#define DH 64
#define HD (NH*DH)
#define BQ 64
#define SPAN (BQ + 256)      // 320 keys staged per block (W<=128)
#define NT 256               // 4 waves; 80 KB LDS -> 2 blocks/CU

// ---------------- prepass: fp32 -> f16, pre-swizzled, K row-major / V transposed ---------
// K_ws[b][h][s][d] f16: 16B chunk cr of row s stored at chunk (cr ^ (s&7)).
// Vt_ws[b][h][d][s] f16: 16B key-chunk kc of dim-row d stored at (kc&~7)|((kc&7)^(d&7)).
// Because attention-block spans start at s0 ≡ 0 (mod 64), the attention kernel's
// swizzled LDS image equals a contiguous byte-copy of these ws regions.
__global__ __launch_bounds__(256)
void swa_prep(const float* __restrict__ kg, const float* __restrict__ vg,
              unsigned short* __restrict__ kws, unsigned short* __restrict__ vtws)
{
    __shared__ unsigned short Vl[64 * 64];   // [row][dim] f16 linear, 8 KB

    const int bid = blockIdx.x;              // 512 = b(2) * h(8) * sb(32)
    const int sb = bid & 31, h = (bid >> 5) & 7, b = bid >> 8;
    const int t = threadIdx.x;

    const float* kin = kg + (((size_t)b * S_LEN + sb * 64) * NH + h) * DH;
    const float* vin = vg + (((size_t)b * S_LEN + sb * 64) * NH + h) * DH;
    unsigned short* kout = kws + ((size_t)(b * NH + h) * S_LEN + sb * 64) * DH;

    // K: 64 rows x 8 chunks = 512 tasks, 2 iters (read 32B fp32 -> write 16B f16)
    #pragma unroll
    for (int it = 0; it < 2; ++it) {
        const int task = t + it * 256;
        const int row = task >> 3, cr = task & 7;
        const int s = sb * 64 + row;
        const f32x4 f0 = *(const f32x4*)(kin + (size_t)row * HD + cr * 8);
        const f32x4 f1 = *(const f32x4*)(kin + (size_t)row * HD + cr * 8 + 4);
        half8 hv;
        #pragma unroll
        for (int e = 0; e < 4; ++e) { hv[e] = (_Float16)f0[e]; hv[4+e] = (_Float16)f1[e]; }
        *(half8*)(&kout[(size_t)row * DH + ((cr ^ (s & 7)) << 3)]) = hv;
    }

    // V -> LDS f16 linear tile
    #pragma unroll
    for (int it = 0; it < 2; ++it) {
        const int task = t + it * 256;
        const int row = task >> 3, cr = task & 7;
        const f32x4 f0 = *(const f32x4*)(vin + (size_t)row * HD + cr * 8);
        const f32x4 f1 = *(const f32x4*)(vin + (size_t)row * HD + cr * 8 + 4);
        half8 hv;
        #pragma unroll
        for (int e = 0; e < 4; ++e) { hv[e] = (_Float16)f0[e]; hv[4+e] = (_Float16)f1[e]; }
        *(half8*)(&Vl[row * 64 + cr * 8]) = hv;
    }
    __syncthreads();

    // gather-transpose out of LDS: task = (kc 0..7, d 0..63)
    unsigned short* vtout = vtws + (size_t)(b * NH + h) * DH * S_LEN;
    #pragma unroll
    for (int it = 0; it < 2; ++it) {
        const int task = t + it * 256;
        const int d = task & 63, kc = task >> 6;
        u16x8 w;
        #pragma unroll
        for (int r = 0; r < 8; ++r) w[r] = Vl[(kc * 8 + r) * 64 + d];
        *(u16x8*)(&vtout[(size_t)d * S_LEN + ((sb * 8 + (kc ^ (d & 7))) << 3)]) = w;
    }
}

// ---------------- attention: R2 structure, staging = async byte-copy from ws ----------
// Swapped QK^T: S^T = K*Q^T -> lane (c,g) holds 8 scores for query q0+16*wid+c.
// PV: O^T = V^T * P^T with K-axis permutation sigma(8g+e)=4g+(e&3)+16*(e>>2)
// so the P fragment is the lane's own 8 probabilities (no repack).
__global__ __launch_bounds__(NT, 2)
void swa_mfma(const float* __restrict__ qg,
              const unsigned short* __restrict__ kws,
              const unsigned short* __restrict__ vtws,
              const int* __restrict__ wptr,
              float* __restrict__ outg)
{
    __shared__ __align__(1024) unsigned short Kl[SPAN * DH];  // [key][dim] f16, swizzled (40 KB)
    __shared__ __align__(1024) unsigned short Vt[DH * SPAN];  // [dim][key] f16, swizzled (40 KB)

    int W = *wptr; if (W > 128) W = 128;

    const int t = threadIdx.x;
    // XCD-aware bijective swizzle (gridDim.x = 512): each XCD's 64 contiguous
    // work-ids = all 32 q-tiles of 2 (b,h) panels.
    int bid = blockIdx.x;
    bid = (bid & 7) * (gridDim.x >> 3) + (bid >> 3);
    const int qt = bid & 31, h = (bid >> 5) & 7, b = bid >> 8;
    const int i0 = qt * BQ, s0 = i0 - W;

    const int wid = t >> 6, lane = t & 63, c = lane & 15, g = lane >> 4;
    const int q = i0 + wid * 16 + c;

    // ---- async staging: LDS image = contiguous slice of pre-swizzled ws ----
    const char* kpan = (const char*)(kws + (size_t)(b * NH + h) * S_LEN * DH);   // rows of 128 B
    const char* vpan = (const char*)(vtws + (size_t)(b * NH + h) * DH * S_LEN);  // rows of 4096 B
    {
        // K: 40960 B, wave wid copies bytes [wid*10240, +10240)
        #pragma unroll
        for (int i = 0; i < 10; ++i) {
            const int off = wid * 10240 + i * 1024 + lane * 16;
            int srow = s0 + (off >> 7);
            srow = srow < 0 ? 0 : (srow > S_LEN - 1 ? S_LEN - 1 : srow);   // clamped rows are masked later
            const void* src = kpan + (size_t)srow * 128 + (off & 127);
            __builtin_amdgcn_global_load_lds(src, (char*)Kl + wid * 10240 + i * 1024, 16, 0, 0);
        }
        // Vt: 40960 B, rows of 640 B per dim
        #pragma unroll
        for (int i = 0; i < 10; ++i) {
            const int off = wid * 10240 + i * 1024 + lane * 16;
            const int d = off / 640;
            const int cbyte = off - d * 640;
            int rb = s0 * 2 + cbyte;                                        // byte pos in 4096-B dim row
            rb = rb < 0 ? 0 : (rb > 4080 ? 4080 : rb);                      // clamped chunks are x0 later
            const void* src = vpan + (size_t)d * 4096 + rb;
            __builtin_amdgcn_global_load_lds(src, (char*)Vt + wid * 10240 + i * 1024, 16, 0, 0);
        }
    }

    // ---- Q fragments from fp32 (1/sqrt(D)*log2(e) folded; exp -> exp2 domain) ----
    const float* qrow = qg + (size_t)b * S_LEN * HD + h * DH + (size_t)q * HD;
    const f32x4 qf0 = *(const f32x4*)(qrow + g * 8);
    const f32x4 qf1 = *(const f32x4*)(qrow + g * 8 + 4);
    const f32x4 qf2 = *(const f32x4*)(qrow + 32 + g * 8);
    const f32x4 qf3 = *(const f32x4*)(qrow + 32 + g * 8 + 4);
    half8 qa0, qa1;
    {
        const float qs = 0.18033688011112042f;  // 0.125 * log2(e)
        #pragma unroll
        for (int e = 0; e < 4; ++e) {
            qa0[e] = (_Float16)(qf0[e] * qs); qa0[4+e] = (_Float16)(qf1[e] * qs);
            qa1[e] = (_Float16)(qf2[e] * qs); qa1[4+e] = (_Float16)(qf3[e] * qs);
        }
    }

    const int c7 = c & 7;
    const int ch0 = (g ^ c7) << 3;
    const int ch1 = ((g + 4) ^ c7) << 3;
    int lo = q - W; if (lo < 0) lo = 0;
    int hi = q + W; if (hi > S_LEN - 1) hi = S_LEN - 1;
    const unsigned rng = (unsigned)(hi - lo);

    int ts = wid >> 1;
    const int ts0 = (s0 < 0) ? ((-s0) >> 5) : 0;
    if (ts0 > ts) ts = ts0;
    const int te_w = (16 * wid + 15 + 2 * W) >> 5;
    const int te_s = (S_LEN - 1 - s0) >> 5;
    const int te = te_w < te_s ? te_w : te_s;

    float m = -1e4f, l = 0.f;
    f32x4 o0 = {0,0,0,0}, o1 = {0,0,0,0}, o2 = {0,0,0,0}, o3 = {0,0,0,0};

    __syncthreads();   // vmcnt(0) drain of global_load_lds + barrier

    for (int t32 = ts; t32 <= te; ++t32) {
        // ---- QK^T (swapped): S^T = K * Q^T ----
        const unsigned short* krow = &Kl[(t32 * 32 + c) * 64];
        half8 k00 = *(const half8*)(krow + ch0);
        half8 k01 = *(const half8*)(krow + ch1);
        half8 k10 = *(const half8*)(krow + 16 * 64 + ch0);
        half8 k11 = *(const half8*)(krow + 16 * 64 + ch1);
        f32x4 st0 = {0,0,0,0}, st1 = {0,0,0,0};
        __builtin_amdgcn_s_setprio(1);
        st0 = __builtin_amdgcn_mfma_f32_16x16x32_f16(k00, qa0, st0, 0, 0, 0);
        st0 = __builtin_amdgcn_mfma_f32_16x16x32_f16(k01, qa1, st0, 0, 0, 0);
        st1 = __builtin_amdgcn_mfma_f32_16x16x32_f16(k10, qa0, st1, 0, 0, 0);
        st1 = __builtin_amdgcn_mfma_f32_16x16x32_f16(k11, qa1, st1, 0, 0, 0);
        __builtin_amdgcn_s_setprio(0);

        // ---- mask + online softmax (lane-local per query) ----
        const int kb = s0 + t32 * 32 + 4 * g;
        float sv0[4], sv1[4];
        #pragma unroll
        for (int r = 0; r < 4; ++r) {
            sv0[r] = ((unsigned)(kb + r - lo) <= rng)      ? st0[r] : -30000.f;
            sv1[r] = ((unsigned)(kb + 16 + r - lo) <= rng) ? st1[r] : -30000.f;
        }
        float tmax = fmaxf(fmaxf(fmaxf(sv0[0], sv0[1]), fmaxf(sv0[2], sv0[3])),
                           fmaxf(fmaxf(sv1[0], sv1[1]), fmaxf(sv1[2], sv1[3])));
        tmax = fmaxf(tmax, __shfl_xor(tmax, 16));
        tmax = fmaxf(tmax, __shfl_xor(tmax, 32));
        if (__any(tmax > m)) {   // deferred rescale
            const float newm = fmaxf(m, tmax);
            const float alpha = exp2f(m - newm);
            m = newm;
            l *= alpha;
            o0 *= alpha; o1 *= alpha; o2 *= alpha; o3 *= alpha;
        }
        float p0[4], p1[4], ls = 0.f;
        #pragma unroll
        for (int r = 0; r < 4; ++r) {
            p0[r] = exp2f(sv0[r] - m);
            p1[r] = exp2f(sv1[r] - m);
            ls += p0[r] + p1[r];
        }
        l += ls;
        half8 pb;
        #pragma unroll
        for (int r = 0; r < 4; ++r) { pb[r] = (_Float16)p0[r]; pb[4+r] = (_Float16)p1[r]; }

        // ---- PV: O^T += V^T * P^T ----
        const int cb = 4 * t32 + (g >> 1);
        const int off1 = ((cb ^ c7) << 3) + ((g & 1) << 2);
        const int off2 = (((cb + 2) ^ c7) << 3) + ((g & 1) << 2);
        __builtin_amdgcn_s_setprio(1);
#define PV_STEP(DF, OACC) { \
        const unsigned short* vrow = &Vt[(16 * DF + c) * SPAN]; \
        half4 vlo = *(const half4*)(vrow + off1); \
        half4 vhi = *(const half4*)(vrow + off2); \
        half8 vf; \
        vf[0]=vlo[0]; vf[1]=vlo[1]; vf[2]=vlo[2]; vf[3]=vlo[3]; \
        vf[4]=vhi[0]; vf[5]=vhi[1]; vf[6]=vhi[2]; vf[7]=vhi[3]; \
        OACC = __builtin_amdgcn_mfma_f32_16x16x32_f16(vf, pb, OACC, 0, 0, 0); }
        PV_STEP(0, o0)
        PV_STEP(1, o1)
        PV_STEP(2, o2)
        PV_STEP(3, o3)
#undef PV_STEP
        __builtin_amdgcn_s_setprio(0);
    }

    // ---- epilogue ----
    l += __shfl_xor(l, 16);
    l += __shfl_xor(l, 32);
    const float inv = 1.0f / l;
    float* orow = outg + (size_t)b * S_LEN * HD + h * DH + (size_t)q * HD + 4 * g;
    { float4 w; w.x=o0[0]*inv; w.y=o0[1]*inv; w.z=o0[2]*inv; w.w=o0[3]*inv; *(float4*)(orow)      = w; }
    { float4 w; w.x=o1[0]*inv; w.y=o1[1]*inv; w.z=o1[2]*inv; w.w=o1[3]*inv; *(float4*)(orow + 16) = w; }
    { float4 w; w.x=o2[0]*inv; w.y=o2[1]*inv; w.z=o2[2]*inv; w.w=o2[3]*inv; *(float4*)(orow + 32) = w; }
    { float4 w; w.x=o3[0]*inv; w.y=o3[1]*inv; w.z=o3[2]*inv; w.w=o3[3]*inv; *(float4*)(orow + 48) = w; }
}

extern "C" void kernel_launch(void* const* d_in, const int* in_sizes, int n_in,
                              void* d_out, int out_size, void* d_ws, size_t ws_size,
                              hipStream_t stream) {
    const float* q = (const float*)d_in[0];
    const float* k = (const float*)d_in[1];
    const float* v = (const float*)d_in[2];
    const int*   w = (const int*)d_in[3];
    float* out = (float*)d_out;

    unsigned short* kws  = (unsigned short*)d_ws;                       // 4 MB f16 K
    unsigned short* vtws = kws + (size_t)2 * NH * S_LEN * DH;           // 4 MB f16 V^T

    swa_prep<<<dim3(512), dim3(256), 0, stream>>>(k, v, kws, vtws);
    swa_mfma<<<dim3(2 * NH * (S_LEN / BQ)), dim3(NT), 0, stream>>>(q, kws, vtws, w, out);
}